// Round 18
// baseline (446.531 us; speedup 1.0000x reference)
//
#include <hip/hip_runtime.h>
#include <stdint.h>

namespace {

constexpr int B = 8;
constexpr int H = 1024;
constexpr int W = 1024;
constexpr int TOPK = 4096;
constexpr int CAND_CAP = 131072;  // per batch
constexpr int SEL_CAP = 16384;    // per batch
constexpr int LIST_CAP = 256;     // per 64x64 tile (round-18: avg ~20 cands/tile,
                                  // >50 sigma margin; overflow path is exact. 320->256
                                  // saves 512B LDS -> 32256 < 163840/5 = 32768, so 5
                                  // blocks/CU fit with headroom; r17's 32768-exact sat
                                  // ON the boundary and occupancy fell 38->34%)

// Fine histogram, 512-bin window (round-17): bucket = (score_bits>>15) - (125<<8),
// clamped to 0. Covers exp 125..126 (scores in [0.25, 1.0)); candidates are 5x5
// local maxima (>= max of 25 uniforms), P(score < 0.25) = 0.25^25 ~ 1e-15. Bin 0
// aggregates underflow -> threshold there = select-all (exactness fallback).
constexpr int HIST_BINS = 512;
constexpr int HIST_BASE = 125 << 8;  // 32000

// fused-NMS tile: 64x64 interior, radius-8 staged halo (round-12 validity chain:
// M0/M1 computed rows [4,75]; emission rows [8,71] = gy in [y0,y0+63]).
constexpr int RROWS = 78;   // staged score rows (gy = y0-8+r)
constexpr int NG = 20;      // float4 col-groups (80 cols, gx0 = x0-8+4G)
constexpr int STR = 80;     // score row stride (floats)
constexpr int MW = 5;       // mask words/row (3 used + 2 zero pad; stride-5 debanks)
constexpr int NSM = 9;      // mask-pass strips: r0 = 4+8s -> rows 4..75
constexpr int NSE = 8;      // emission strips:  r0 = 8+8s -> rows 8..71
constexpr int NUNIT_M = NG * NSM;  // 180
constexpr int NUNIT_E = NG * NSE;  // 160
// Round-13 lesson: __launch_bounds__(256,5) spilled the ring state. Keep min-4
// (the 5th block comes from LDS headroom, not an allocator cap).
// LDS: S 24960 + masks 2*1560 + list 2048 + hist 2048 + ~16 = ~32.2 KiB.

// rank kernel tiling (round-5 lesson: 2D (me,chunk) split keeps ~680 blocks active)
constexpr int RK_ME = 256;   // me-keys per block (1/thread)
constexpr int RK_CH = 1024;  // chunk keys staged in LDS per block

// workspace layout (bytes).
// Rounds 9/15 lesson: intra-kernel cross-block sync (grid.sync OR point-to-point
// done counters) costs per-XCD L2 flush storms on 8-XCD MI355X — kernel
// boundaries are the cheapest sync. Pipeline: memset + 4 kernels.
constexpr size_t OFF_CNT   = 0;                                    // 4 KiB
constexpr size_t OFF_GH    = 4096;                                 // B*512*4 = 16 KiB
constexpr size_t OFF_RANK  = OFF_GH + (size_t)B * HIST_BINS * 4;   // 512 KiB
constexpr size_t OFF_SEL   = OFF_RANK + (size_t)B * SEL_CAP * 4;   // 1 MiB
constexpr size_t OFF_CAND  = OFF_SEL + (size_t)B * SEL_CAP * 8;    // 8 MiB
constexpr size_t MEMSET_BYTES = OFF_RANK;  // cnt page + ghist (20 KiB)

__device__ __forceinline__ float max5(float a, float b, float c, float d, float e) {
  return fmaxf(fmaxf(fmaxf(a, b), fmaxf(c, d)), e);
}
__device__ __forceinline__ float4 ld4(const float* p) {
  return *reinterpret_cast<const float4*>(p);
}

// One unit: col-group G in [0,NG), strip s -> output rows r0..r0+7, where
// r0 = 4+8s for mask passes (0/1) and 8+8s for emission (2). PASS 0: plain
// local-max -> M0. PASS 1/2: inline dilation of the previous mask via a
// 2-row-lookahead ring. PASS 1 writes cumulative M1 = M0|new. PASS 2 emits
// candidates into the LDS list (overflow keys append+hist globally — rare).
template <int PASS>
__device__ __forceinline__ void score_pass(
    int u, int x0, int y0, const float* __restrict__ S,
    const uint32_t* __restrict__ MIN_, uint32_t* __restrict__ MOUT,
    uint64_t* list, uint32_t* cnt_loc, uint64_t* cand, uint32_t* cand_count,
    uint32_t* __restrict__ ghist, int b) {
  const int G = u % NG, s = u / NG;
  const int r0 = ((PASS == 2) ? 8 : 4) + 8 * s;
  const int gx0 = x0 - 8 + 4 * G;
  uint32_t colm = 0;
#pragma unroll
  for (int j = 0; j < 4; ++j)
    if ((unsigned)(gx0 + j) < (unsigned)W) colm |= 1u << j;

  // 16-col mask window starting at p2 = 4G-6 (covers 5-wide OR for 12 score cols)
  const int p2 = 4 * G - 6;
  const int pw2 = (p2 < 0) ? 0 : (p2 >> 5);
  const int psh2 = (p2 < 0) ? 0 : (p2 & 31);
  const int pls2 = (p2 < 0) ? -p2 : 0;

  float4 hw[5], cw[5];
  uint32_t snr[5], mor[5], cnb[5];
  constexpr int NK = (PASS == 0) ? 12 : 16;
#pragma unroll
  for (int k = 0; k < NK; ++k) {
    if (PASS != 0) {
      const int mr = r0 - 4 + k;
      uint32_t morrow = 0, cnib = 0;
      if ((unsigned)mr < (unsigned)RROWS) {
        const uint32_t* srow = MIN_ + mr * MW;
        uint64_t X = (uint64_t)srow[pw2] | ((uint64_t)srow[pw2 + 1] << 32);
        uint64_t win = pls2 ? (X << pls2) : (X >> psh2);
        uint64_t t5 = win | (win >> 1) | (win >> 2) | (win >> 3) | (win >> 4);
        morrow = (uint32_t)t5 & 0xFFFu;
        cnib = (uint32_t)(win >> 6) & 0xFu;
      }
      mor[k % 5] = morrow;
      cnb[k % 5] = cnib;
    }
    const int ks = (PASS == 0) ? k : k - 4;
    if (ks >= 0) {
      const int sr = r0 - 2 + ks;
      uint32_t supp = 0;
      if (PASS != 0) supp = mor[0] | mor[1] | mor[2] | mor[3] | mor[4];
      const float* rowp = S + sr * STR + 4 * G;
      float4 d = ld4(rowp);
      float4 a = (G > 0) ? ld4(rowp - 4) : d;  // garbage-only cols, safe
      float4 e = (G < NG - 1) ? ld4(rowp + 4) : d;
      if (PASS != 0) {
        if (supp & 0x001u) a.x = 0.f;
        if (supp & 0x002u) a.y = 0.f;
        if (supp & 0x004u) a.z = 0.f;
        if (supp & 0x008u) a.w = 0.f;
        if (supp & 0x010u) d.x = 0.f;
        if (supp & 0x020u) d.y = 0.f;
        if (supp & 0x040u) d.z = 0.f;
        if (supp & 0x080u) d.w = 0.f;
        if (supp & 0x100u) e.x = 0.f;
        if (supp & 0x200u) e.y = 0.f;
        if (supp & 0x400u) e.z = 0.f;
        if (supp & 0x800u) e.w = 0.f;
      }
      float4 hm;
      hm.x = max5(a.z, a.w, d.x, d.y, d.z);
      hm.y = max5(a.w, d.x, d.y, d.z, d.w);
      hm.z = max5(d.x, d.y, d.z, d.w, e.x);
      hm.w = max5(d.y, d.z, d.w, e.x, e.y);
      hw[ks % 5] = hm;
      cw[ks % 5] = d;
      snr[ks % 5] = (supp >> 4) & 0xFu;
      if (ks >= 4) {
        const int rq = r0 - 4 + ks;  // output row: r0..r0+7
        const int gy = y0 - 8 + rq;
        float4 vm;
        vm.x = max5(hw[0].x, hw[1].x, hw[2].x, hw[3].x, hw[4].x);
        vm.y = max5(hw[0].y, hw[1].y, hw[2].y, hw[3].y, hw[4].y);
        vm.z = max5(hw[0].z, hw[1].z, hw[2].z, hw[3].z, hw[4].z);
        vm.w = max5(hw[0].w, hw[1].w, hw[2].w, hw[3].w, hw[4].w);
        float4 c = cw[(ks + 3) % 5];  // center (masked for PASS 1/2)
        uint32_t nm = (uint32_t)(c.x == vm.x) | ((uint32_t)(c.y == vm.y) << 1) |
                      ((uint32_t)(c.z == vm.z) << 2) | ((uint32_t)(c.w == vm.w) << 3);
        nm &= ((unsigned)gy < (unsigned)H) ? colm : 0u;
        const int widx = rq * MW + (G >> 3);
        const int shift = 4 * (G & 7);
        if (PASS == 0) {
          if (nm) atomicOr(&MOUT[widx], nm << shift);
        } else if (PASS == 1) {
          uint32_t fin = cnb[ks % 5] | (nm & ~snr[(ks + 3) % 5]);
          if (fin) atomicOr(&MOUT[widx], fin << shift);
        } else {
          uint32_t fin = cnb[ks % 5] | (nm & ~snr[(ks + 3) % 5]);
          if (fin && G >= 2 && G < 18 && gy >= 2 && gy < H - 2) {
#pragma unroll
            for (int j = 0; j < 4; ++j) {
              if ((fin >> j) & 1u) {
                int gx = gx0 + j;
                if (gx >= 2 && gx < W - 2) {
                  float sval = S[rq * STR + 4 * G + j];  // original (unmasked) score
                  if (sval > 0.0f) {
                    uint32_t bits = __float_as_uint(sval);
                    uint32_t flat = (uint32_t)(gy * W + gx);
                    uint64_t key = ((uint64_t)bits << 32) | (uint64_t)(0xFFFFFFFFu - flat);
                    uint32_t pos = atomicAdd(cnt_loc, 1u);
                    if (pos < (uint32_t)LIST_CAP) {
                      list[pos] = key;
                    } else {  // tie overflow: direct global append + hist (rare)
                      uint32_t pp = atomicAdd(&cand_count[b], 1u);
                      if (pp < (uint32_t)CAND_CAP) cand[(size_t)b * CAND_CAP + pp] = key;
                      int bin = (int)(bits >> 15) - HIST_BASE;
                      if (bin < 0) bin = 0;
                      if (bin >= HIST_BINS) bin = HIST_BINS - 1;
                      atomicAdd(&ghist[(size_t)b * HIST_BINS + bin], 1u);
                    }
                  }
                }
              }
            }
          }
        }
      }
    }
  }
}

// ---------------- fused 3-pass NMS + candidate emit + fine-hist tail -----------------
__global__ void __launch_bounds__(256, 4) k_nms(const float* __restrict__ scores,
                                                uint64_t* __restrict__ cand,
                                                uint32_t* __restrict__ cand_count,
                                                uint32_t* __restrict__ ghist) {
  __shared__ float S[RROWS * STR];
  __shared__ uint32_t M0s[RROWS * MW];
  __shared__ uint32_t M1s[RROWS * MW];
  __shared__ uint64_t list[LIST_CAP];
  __shared__ uint32_t Shist[HIST_BINS];
  __shared__ uint32_t cnt_loc, base_g;
  const int b = blockIdx.z;
  const int x0 = blockIdx.x * 64, y0 = blockIdx.y * 64;
  const int tid = threadIdx.x;
  const float* img = scores + (size_t)b * H * W;
  if (tid == 0) cnt_loc = 0;

  for (int u = tid; u < RROWS * NG; u += 256) {
    int r = u / NG, G = u % NG;
    int gy = y0 - 8 + r, gx = x0 - 8 + 4 * G;
    float4 v;
    if ((unsigned)gy < (unsigned)H && (unsigned)gx < (unsigned)W)
      v = ld4(img + (size_t)gy * W + gx);
    else
      v = make_float4(-INFINITY, -INFINITY, -INFINITY, -INFINITY);
    *reinterpret_cast<float4*>(&S[r * STR + 4 * G]) = v;
  }
  for (int i = tid; i < RROWS * MW; i += 256) {
    M0s[i] = 0;
    M1s[i] = 0;
  }
  __syncthreads();
  if (tid < NUNIT_M) {
    score_pass<0>(tid, x0, y0, S, nullptr, M0s, nullptr, nullptr, nullptr, nullptr,
                  nullptr, b);
  } else {  // 76 idle threads zero the hist during pass 0 (no barriers either side)
    for (int i = tid - NUNIT_M; i < HIST_BINS; i += 256 - NUNIT_M) Shist[i] = 0;
  }
  __syncthreads();
  if (tid < NUNIT_M)
    score_pass<1>(tid, x0, y0, S, M0s, M1s, nullptr, nullptr, nullptr, nullptr,
                  nullptr, b);
  __syncthreads();
  if (tid < NUNIT_E)
    score_pass<2>(tid, x0, y0, S, M1s, nullptr, list, &cnt_loc, cand, cand_count,
                  ghist, b);
  __syncthreads();
  // tail: copy list -> cand, accumulate 512-bin fine hist, sparse-merge to global
  uint32_t nblk = cnt_loc;
  uint32_t nmain = nblk < (uint32_t)LIST_CAP ? nblk : (uint32_t)LIST_CAP;
  if (tid == 0) base_g = atomicAdd(&cand_count[b], nmain);
  __syncthreads();
  uint32_t bg = base_g;
  for (uint32_t i = tid; i < nmain; i += 256) {
    uint64_t key = list[i];
    uint32_t pp = bg + i;
    if (pp < (uint32_t)CAND_CAP) cand[(size_t)b * CAND_CAP + pp] = key;
    int bin = (int)(uint32_t)(key >> 47) - HIST_BASE;  // = (score_bits>>15)-32000
    if (bin < 0) bin = 0;
    atomicAdd(&Shist[bin], 1u);
  }
  __syncthreads();
#pragma unroll
  for (int rr = 0; rr < HIST_BINS / 256; ++rr) {
    uint32_t v = Shist[rr * 256 + tid];
    if (v) atomicAdd(&ghist[(size_t)b * HIST_BINS + rr * 256 + tid], v);
  }
}

// ---------------- compact (threshold-find fused in, 512-bin hist) --------------------
// Each live block recomputes thr from ghist with a 128-wide suffix scan (redundant
// across blocks but fully parallel), filters its 1024-candidate slice, and zeroes
// rankg for every sel slot written. Dead blocks (beyond cand count) exit early.
__global__ void __launch_bounds__(1024) k_compact(const uint64_t* __restrict__ cand,
                                                  const uint32_t* __restrict__ cand_count,
                                                  const uint32_t* __restrict__ ghist,
                                                  uint64_t* __restrict__ sel,
                                                  uint32_t* __restrict__ sel_count,
                                                  uint32_t* __restrict__ rankg) {
  __shared__ uint64_t list[1024];
  __shared__ uint32_t cnt_loc, base_g;
  __shared__ uint32_t h[128];
  __shared__ uint64_t s_thr;
  const int b = blockIdx.y;
  uint32_t n = cand_count[b];
  if (n > (uint32_t)CAND_CAP) n = CAND_CAP;
  if (blockIdx.x * 1024u >= n) return;  // dead block: skip redundant scan
  const int tid = threadIdx.x;
  if (tid == 0) {
    cnt_loc = 0;
    s_thr = 0ull;
  }
  // bins 4*tid .. 4*tid+3 (512/4 = 128 loaders)
  const uint32_t* gh = ghist + (size_t)b * HIST_BINS;
  uint4 mybins = make_uint4(0u, 0u, 0u, 0u);
  if (tid < HIST_BINS / 4) {
    mybins = reinterpret_cast<const uint4*>(gh)[tid];
    h[tid] = mybins.x + mybins.y + mybins.z + mybins.w;
  }
  __syncthreads();
  for (int d = 1; d < 128; d <<= 1) {
    uint32_t v = 0;
    if (tid < 128) v = (tid + d < 128) ? h[tid + d] : 0u;
    __syncthreads();
    if (tid < 128) h[tid] += v;
    __syncthreads();
  }
  if (tid < 128) {
    uint32_t cum = h[tid];                        // count in bins >= 4*tid
    uint32_t nxt = (tid < 127) ? h[tid + 1] : 0u; // count in bins >= 4*(tid+1)
    if (cum >= (uint32_t)TOPK && nxt < (uint32_t)TOPK) {
      uint32_t run = nxt;
      uint32_t binv[4] = {mybins.x, mybins.y, mybins.z, mybins.w};
      int thrbin = 4 * tid;
#pragma unroll
      for (int j = 3; j >= 0; --j) {
        run += binv[j];
        if (run >= (uint32_t)TOPK) {
          thrbin = 4 * tid + j;
          break;
        }
      }
      if (thrbin > 0)
        s_thr = ((uint64_t)(uint32_t)(thrbin + HIST_BASE)) << 47;
      // thrbin == 0: underflow aggregate -> thr 0 (select all)
    }
  }
  __syncthreads();
  const uint64_t thr = s_thr;  // 0 => select all (fewer than TOPK, or bin-0 thr)
  uint32_t i = blockIdx.x * 1024 + tid;
  if (i < n) {
    uint64_t key = cand[(size_t)b * CAND_CAP + i];
    if (key >= thr) {
      uint32_t pos = atomicAdd(&cnt_loc, 1u);
      list[pos] = key;
    }
  }
  __syncthreads();
  uint32_t nblk = cnt_loc;
  if (tid == 0 && nblk > 0) base_g = atomicAdd(&sel_count[b], nblk);
  __syncthreads();
  if (nblk > 0 && (uint32_t)tid < nblk) {
    uint32_t pp = base_g + tid;
    if (pp < (uint32_t)SEL_CAP) {
      sel[(size_t)b * SEL_CAP + pp] = list[tid];
      rankg[(size_t)b * SEL_CAP + pp] = 0u;
    }
  }
}

// ---------------- tiled partial ranking ----------------------------------------------
__global__ void __launch_bounds__(RK_ME) k_rank_part(const uint64_t* __restrict__ sel,
                                                     const uint32_t* __restrict__ sel_count,
                                                     uint32_t* __restrict__ rankg) {
  __shared__ uint64_t keys[RK_CH];  // 8 KiB
  const int b = blockIdx.z;
  uint32_t n = sel_count[b];
  if (n > (uint32_t)SEL_CAP) n = SEL_CAP;
  const uint32_t me0 = blockIdx.x * RK_ME;
  const uint32_t c0 = blockIdx.y * RK_CH;
  if (me0 >= n || c0 >= n) return;
  const uint64_t* sb = sel + (size_t)b * SEL_CAP;
  uint32_t clen = n - c0;
  if (clen > (uint32_t)RK_CH) clen = RK_CH;
  for (uint32_t i = threadIdx.x; i < clen; i += RK_ME) keys[i] = sb[c0 + i];
  __syncthreads();
  const uint32_t me = me0 + threadIdx.x;
  if (me >= n) return;
  const uint64_t kme = sb[me];
  uint32_t rank = 0;
  uint32_t i = 0;
  for (; i + 8 <= clen; i += 8) {
    rank += (keys[i] > kme);
    rank += (keys[i + 1] > kme);
    rank += (keys[i + 2] > kme);
    rank += (keys[i + 3] > kme);
    rank += (keys[i + 4] > kme);
    rank += (keys[i + 5] > kme);
    rank += (keys[i + 6] > kme);
    rank += (keys[i + 7] > kme);
  }
  for (; i < clen; ++i) rank += (keys[i] > kme);
  if (rank) atomicAdd(&rankg[(size_t)b * SEL_CAP + me], rank);
}

// ---------------- refinement (scatter fused in): 8 lanes per sel item ----------------
__global__ void __launch_bounds__(256) k_refine(const float* __restrict__ scores,
                                                const uint64_t* __restrict__ sel,
                                                const uint32_t* __restrict__ sel_count,
                                                const uint32_t* __restrict__ rankg,
                                                float* __restrict__ out) {
  int gid = blockIdx.x * 256 + threadIdx.x;
  int idx = gid >> 3, ln = gid & 7;
  const int b = idx / SEL_CAP;
  const int i = idx % SEL_CAP;
  uint32_t n = sel_count[b];
  if (n > (uint32_t)SEL_CAP) n = SEL_CAP;
  if ((uint32_t)i >= n) return;  // uniform across the 8-lane group
  uint32_t r = rankg[(size_t)b * SEL_CAP + i];
  if (r >= (uint32_t)TOPK) return;  // uniform across the group
  uint64_t key = sel[(size_t)b * SEL_CAP + i];
  uint32_t flat = 0xFFFFFFFFu - (uint32_t)(key & 0xFFFFFFFFull);
  if (flat >= (uint32_t)(H * W)) flat = 0;  // safety guard
  const int ix = (int)(flat % W);
  const int iy = (int)(flat / W);
  const float* img = scores + (size_t)b * H * W;

  const int nt = (ln == 0) ? 4 : 3;
  float v[4];
  float mymax = -INFINITY;
#pragma unroll
  for (int q = 0; q < 4; ++q) {
    if (q < nt) {
      int t = ln + 8 * q;
      int y = iy + t / 5 - 2, x = ix + t % 5 - 2;
      float val = ((unsigned)x < (unsigned)W && (unsigned)y < (unsigned)H)
                      ? img[(size_t)y * W + x] : 0.0f;
      v[q] = val;
      mymax = fmaxf(mymax, val);
    }
  }
#pragma unroll
  for (int m = 1; m < 8; m <<= 1) mymax = fmaxf(mymax, __shfl_xor(mymax, m));
  float e[4];
  float sum = 0.f, sx = 0.f, sy = 0.f;
#pragma unroll
  for (int q = 0; q < 4; ++q) {
    if (q < nt) {
      int t = ln + 8 * q;
      float ev = expf((v[q] - mymax) / 0.1f);
      e[q] = ev;
      sum += ev;
      sx += ev * (float)(t % 5 - 2);
      sy += ev * (float)(t / 5 - 2);
    }
  }
#pragma unroll
  for (int m = 1; m < 8; m <<= 1) {
    sum += __shfl_xor(sum, m);
    sx += __shfl_xor(sx, m);
    sy += __shfl_xor(sy, m);
  }
  float rx = sx / sum, ry = sy / sum;
  float dsp = 0.f;
#pragma unroll
  for (int q = 0; q < 4; ++q) {
    if (q < nt) {
      int t = ln + 8 * q;
      float dx = ((float)(t % 5 - 2) - rx) * 0.5f;
      float dy = ((float)(t / 5 - 2) - ry) * 0.5f;
      dsp += e[q] * (dx * dx + dy * dy);
    }
  }
#pragma unroll
  for (int m = 1; m < 8; m <<= 1) dsp += __shfl_xor(dsp, m);
  if (ln != 0) return;
  dsp /= sum;
  float kx = ((float)ix + rx) / 1023.0f * 2.0f - 1.0f;
  float ky = ((float)iy + ry) / 1023.0f * 2.0f - 1.0f;
  float px = (kx + 1.0f) * 0.5f * 1023.0f;
  float py = (ky + 1.0f) * 0.5f * 1023.0f;
  float x0f = floorf(px), y0f = floorf(py);
  float wx1 = px - x0f, wx0 = 1.0f - wx1;
  float wy1 = py - y0f, wy0 = 1.0f - wy1;
  int x0 = (int)x0f, y0 = (int)y0f;
  float sc = 0.0f;
  {
    int xs[2] = {x0, x0 + 1};
    int ys[2] = {y0, y0 + 1};
    float wxs[2] = {wx0, wx1};
    float wys[2] = {wy0, wy1};
#pragma unroll
    for (int yy = 0; yy < 2; ++yy)
#pragma unroll
      for (int xx = 0; xx < 2; ++xx) {
        int xi = xs[xx], yi = ys[yy];
        bool valid = (xi >= 0 && xi < W && yi >= 0 && yi < H);
        int xc = min(max(xi, 0), W - 1);
        int yc = min(max(yi, 0), H - 1);
        float vv = valid ? img[(size_t)yc * W + xc] : 0.0f;
        sc += vv * (wxs[xx] * wys[yy]);
      }
  }
  out[((size_t)b * TOPK + r) * 2 + 0] = kx;
  out[((size_t)b * TOPK + r) * 2 + 1] = ky;
  out[(size_t)B * TOPK * 2 + (size_t)b * TOPK + r] = sc;
  out[(size_t)B * TOPK * 3 + (size_t)b * TOPK + r] = dsp;
}

}  // namespace

extern "C" void kernel_launch(void* const* d_in, const int* in_sizes, int n_in,
                              void* d_out, int out_size, void* d_ws, size_t ws_size,
                              hipStream_t stream) {
  const float* scores = (const float*)d_in[0];
  float* out = (float*)d_out;
  char* ws = (char*)d_ws;

  uint32_t* cnt = (uint32_t*)(ws + OFF_CNT);
  uint32_t* cand_count = cnt;                    // [B]
  uint32_t* sel_count  = cnt + 8;                // [B]
  uint32_t* ghist = (uint32_t*)(ws + OFF_GH);    // [B][HIST_BINS]
  uint32_t* rankg = (uint32_t*)(ws + OFF_RANK);  // [B][SEL_CAP]
  uint64_t* sel  = (uint64_t*)(ws + OFF_SEL);
  uint64_t* cand = (uint64_t*)(ws + OFF_CAND);

  hipMemsetAsync(ws + OFF_CNT, 0, MEMSET_BYTES, stream);

  k_nms<<<dim3(W / 64, H / 64, B), 256, 0, stream>>>(scores, cand, cand_count, ghist);
  k_compact<<<dim3(CAND_CAP / 1024, B), 1024, 0, stream>>>(cand, cand_count, ghist,
                                                           sel, sel_count, rankg);
  k_rank_part<<<dim3(SEL_CAP / RK_ME, SEL_CAP / RK_CH, B), RK_ME, 0, stream>>>(
      sel, sel_count, rankg);
  k_refine<<<(B * SEL_CAP * 8) / 256, 256, 0, stream>>>(scores, sel, sel_count, rankg,
                                                        out);
}

// Round 19
// 184.802 us; speedup vs baseline: 2.4163x; 2.4163x over previous
//
#include <hip/hip_runtime.h>
#include <stdint.h>

namespace {

constexpr int B = 8;
constexpr int H = 1024;
constexpr int W = 1024;
constexpr int TOPK = 4096;
constexpr int CAND_CAP = 131072;  // per batch
constexpr int SEL_CAP = 16384;    // per batch
constexpr int LIST_CAP = 320;     // per 64x64 tile. ROUND-18 LESSON: mean is ~164
                                  // cands/tile (42k/batch over 256 tiles/batch — NOT
                                  // 2048; r18's cap=256 overflowed a large fraction of
                                  // tiles into the per-candidate hot-bin global-atomic
                                  // fallback = round-1 XCD contention, 65->325us).
                                  // 320 is the calibrated value from round 0.

// Fine histogram, 256-bin window (round-19): bucket = (score_bits>>15) - (126<<8),
// clamped to 0. Covers exp 126 (scores in [0.5, 1.0)); candidates are 5x5 local
// maxima (>= max of 25 uniforms), P(score < 0.5) = 0.5^25 ~ 3e-8. Bin 0 aggregates
// underflow -> threshold there = select-all (exactness fallback). Threshold lands
// ~0.996 (4k of 42k), deep inside exp 126 — resolution unchanged vs the 512-bin
// scheme (mantissa/256 within exp 126). Saves 1 KiB LDS vs r17/18 so LIST_CAP=320
// AND 5 blocks/CU both fit: LDS ~31.7 KiB, 5x31680 = 158400 <= 163840 with margin
// (r17 sat exactly ON the 32768 boundary and occupancy fell).
constexpr int HIST_BINS = 256;
constexpr int HIST_BASE = 126 << 8;  // 32256

// fused-NMS tile: 64x64 interior, radius-8 staged halo (round-12 validity chain:
// M0/M1 computed rows [4,75]; emission rows [8,71] = gy in [y0,y0+63]).
constexpr int RROWS = 78;   // staged score rows (gy = y0-8+r)
constexpr int NG = 20;      // float4 col-groups (80 cols, gx0 = x0-8+4G)
constexpr int STR = 80;     // score row stride (floats)
constexpr int MW = 5;       // mask words/row (3 used + 2 zero pad; stride-5 debanks)
constexpr int NSM = 9;      // mask-pass strips: r0 = 4+8s -> rows 4..75
constexpr int NSE = 8;      // emission strips:  r0 = 8+8s -> rows 8..71
constexpr int NUNIT_M = NG * NSM;  // 180
constexpr int NUNIT_E = NG * NSE;  // 160
// Round-13 lesson: __launch_bounds__(256,5) spilled the ring state. Keep min-4
// (the 5th block comes from LDS headroom, not an allocator cap).

// rank kernel tiling (round-5 lesson: 2D (me,chunk) split keeps ~680 blocks active)
constexpr int RK_ME = 256;   // me-keys per block (1/thread)
constexpr int RK_CH = 1024;  // chunk keys staged in LDS per block

// workspace layout (bytes).
// Rounds 9/15 lesson: intra-kernel cross-block sync (grid.sync OR point-to-point
// done counters) costs per-XCD L2 flush storms on 8-XCD MI355X — kernel
// boundaries are the cheapest sync. Pipeline: memset + 4 kernels.
constexpr size_t OFF_CNT   = 0;                                    // 4 KiB
constexpr size_t OFF_GH    = 4096;                                 // B*256*4 = 8 KiB
constexpr size_t OFF_RANK  = OFF_GH + (size_t)B * HIST_BINS * 4;   // 512 KiB
constexpr size_t OFF_SEL   = OFF_RANK + (size_t)B * SEL_CAP * 4;   // 1 MiB
constexpr size_t OFF_CAND  = OFF_SEL + (size_t)B * SEL_CAP * 8;    // 8 MiB
constexpr size_t MEMSET_BYTES = OFF_RANK;  // cnt page + ghist (12 KiB)

__device__ __forceinline__ float max5(float a, float b, float c, float d, float e) {
  return fmaxf(fmaxf(fmaxf(a, b), fmaxf(c, d)), e);
}
__device__ __forceinline__ float4 ld4(const float* p) {
  return *reinterpret_cast<const float4*>(p);
}

// One unit: col-group G in [0,NG), strip s -> output rows r0..r0+7, where
// r0 = 4+8s for mask passes (0/1) and 8+8s for emission (2). PASS 0: plain
// local-max -> M0. PASS 1/2: inline dilation of the previous mask via a
// 2-row-lookahead ring. PASS 1 writes cumulative M1 = M0|new. PASS 2 emits
// candidates into the LDS list (overflow keys append+hist globally — rare at
// cap 320, ~12 sigma above the 164 mean).
template <int PASS>
__device__ __forceinline__ void score_pass(
    int u, int x0, int y0, const float* __restrict__ S,
    const uint32_t* __restrict__ MIN_, uint32_t* __restrict__ MOUT,
    uint64_t* list, uint32_t* cnt_loc, uint64_t* cand, uint32_t* cand_count,
    uint32_t* __restrict__ ghist, int b) {
  const int G = u % NG, s = u / NG;
  const int r0 = ((PASS == 2) ? 8 : 4) + 8 * s;
  const int gx0 = x0 - 8 + 4 * G;
  uint32_t colm = 0;
#pragma unroll
  for (int j = 0; j < 4; ++j)
    if ((unsigned)(gx0 + j) < (unsigned)W) colm |= 1u << j;

  // 16-col mask window starting at p2 = 4G-6 (covers 5-wide OR for 12 score cols)
  const int p2 = 4 * G - 6;
  const int pw2 = (p2 < 0) ? 0 : (p2 >> 5);
  const int psh2 = (p2 < 0) ? 0 : (p2 & 31);
  const int pls2 = (p2 < 0) ? -p2 : 0;

  float4 hw[5], cw[5];
  uint32_t snr[5], mor[5], cnb[5];
  constexpr int NK = (PASS == 0) ? 12 : 16;
#pragma unroll
  for (int k = 0; k < NK; ++k) {
    if (PASS != 0) {
      const int mr = r0 - 4 + k;
      uint32_t morrow = 0, cnib = 0;
      if ((unsigned)mr < (unsigned)RROWS) {
        const uint32_t* srow = MIN_ + mr * MW;
        uint64_t X = (uint64_t)srow[pw2] | ((uint64_t)srow[pw2 + 1] << 32);
        uint64_t win = pls2 ? (X << pls2) : (X >> psh2);
        uint64_t t5 = win | (win >> 1) | (win >> 2) | (win >> 3) | (win >> 4);
        morrow = (uint32_t)t5 & 0xFFFu;
        cnib = (uint32_t)(win >> 6) & 0xFu;
      }
      mor[k % 5] = morrow;
      cnb[k % 5] = cnib;
    }
    const int ks = (PASS == 0) ? k : k - 4;
    if (ks >= 0) {
      const int sr = r0 - 2 + ks;
      uint32_t supp = 0;
      if (PASS != 0) supp = mor[0] | mor[1] | mor[2] | mor[3] | mor[4];
      const float* rowp = S + sr * STR + 4 * G;
      float4 d = ld4(rowp);
      float4 a = (G > 0) ? ld4(rowp - 4) : d;  // garbage-only cols, safe
      float4 e = (G < NG - 1) ? ld4(rowp + 4) : d;
      if (PASS != 0) {
        if (supp & 0x001u) a.x = 0.f;
        if (supp & 0x002u) a.y = 0.f;
        if (supp & 0x004u) a.z = 0.f;
        if (supp & 0x008u) a.w = 0.f;
        if (supp & 0x010u) d.x = 0.f;
        if (supp & 0x020u) d.y = 0.f;
        if (supp & 0x040u) d.z = 0.f;
        if (supp & 0x080u) d.w = 0.f;
        if (supp & 0x100u) e.x = 0.f;
        if (supp & 0x200u) e.y = 0.f;
        if (supp & 0x400u) e.z = 0.f;
        if (supp & 0x800u) e.w = 0.f;
      }
      float4 hm;
      hm.x = max5(a.z, a.w, d.x, d.y, d.z);
      hm.y = max5(a.w, d.x, d.y, d.z, d.w);
      hm.z = max5(d.x, d.y, d.z, d.w, e.x);
      hm.w = max5(d.y, d.z, d.w, e.x, e.y);
      hw[ks % 5] = hm;
      cw[ks % 5] = d;
      snr[ks % 5] = (supp >> 4) & 0xFu;
      if (ks >= 4) {
        const int rq = r0 - 4 + ks;  // output row: r0..r0+7
        const int gy = y0 - 8 + rq;
        float4 vm;
        vm.x = max5(hw[0].x, hw[1].x, hw[2].x, hw[3].x, hw[4].x);
        vm.y = max5(hw[0].y, hw[1].y, hw[2].y, hw[3].y, hw[4].y);
        vm.z = max5(hw[0].z, hw[1].z, hw[2].z, hw[3].z, hw[4].z);
        vm.w = max5(hw[0].w, hw[1].w, hw[2].w, hw[3].w, hw[4].w);
        float4 c = cw[(ks + 3) % 5];  // center (masked for PASS 1/2)
        uint32_t nm = (uint32_t)(c.x == vm.x) | ((uint32_t)(c.y == vm.y) << 1) |
                      ((uint32_t)(c.z == vm.z) << 2) | ((uint32_t)(c.w == vm.w) << 3);
        nm &= ((unsigned)gy < (unsigned)H) ? colm : 0u;
        const int widx = rq * MW + (G >> 3);
        const int shift = 4 * (G & 7);
        if (PASS == 0) {
          if (nm) atomicOr(&MOUT[widx], nm << shift);
        } else if (PASS == 1) {
          uint32_t fin = cnb[ks % 5] | (nm & ~snr[(ks + 3) % 5]);
          if (fin) atomicOr(&MOUT[widx], fin << shift);
        } else {
          uint32_t fin = cnb[ks % 5] | (nm & ~snr[(ks + 3) % 5]);
          if (fin && G >= 2 && G < 18 && gy >= 2 && gy < H - 2) {
#pragma unroll
            for (int j = 0; j < 4; ++j) {
              if ((fin >> j) & 1u) {
                int gx = gx0 + j;
                if (gx >= 2 && gx < W - 2) {
                  float sval = S[rq * STR + 4 * G + j];  // original (unmasked) score
                  if (sval > 0.0f) {
                    uint32_t bits = __float_as_uint(sval);
                    uint32_t flat = (uint32_t)(gy * W + gx);
                    uint64_t key = ((uint64_t)bits << 32) | (uint64_t)(0xFFFFFFFFu - flat);
                    uint32_t pos = atomicAdd(cnt_loc, 1u);
                    if (pos < (uint32_t)LIST_CAP) {
                      list[pos] = key;
                    } else {  // tie overflow: direct global append + hist (rare)
                      uint32_t pp = atomicAdd(&cand_count[b], 1u);
                      if (pp < (uint32_t)CAND_CAP) cand[(size_t)b * CAND_CAP + pp] = key;
                      int bin = (int)(bits >> 15) - HIST_BASE;
                      if (bin < 0) bin = 0;
                      if (bin >= HIST_BINS) bin = HIST_BINS - 1;
                      atomicAdd(&ghist[(size_t)b * HIST_BINS + bin], 1u);
                    }
                  }
                }
              }
            }
          }
        }
      }
    }
  }
}

// ---------------- fused 3-pass NMS + candidate emit + fine-hist tail -----------------
__global__ void __launch_bounds__(256, 4) k_nms(const float* __restrict__ scores,
                                                uint64_t* __restrict__ cand,
                                                uint32_t* __restrict__ cand_count,
                                                uint32_t* __restrict__ ghist) {
  __shared__ float S[RROWS * STR];
  __shared__ uint32_t M0s[RROWS * MW];
  __shared__ uint32_t M1s[RROWS * MW];
  __shared__ uint64_t list[LIST_CAP];
  __shared__ uint32_t Shist[HIST_BINS];
  __shared__ uint32_t cnt_loc, base_g;
  const int b = blockIdx.z;
  const int x0 = blockIdx.x * 64, y0 = blockIdx.y * 64;
  const int tid = threadIdx.x;
  const float* img = scores + (size_t)b * H * W;
  if (tid == 0) cnt_loc = 0;

  for (int u = tid; u < RROWS * NG; u += 256) {
    int r = u / NG, G = u % NG;
    int gy = y0 - 8 + r, gx = x0 - 8 + 4 * G;
    float4 v;
    if ((unsigned)gy < (unsigned)H && (unsigned)gx < (unsigned)W)
      v = ld4(img + (size_t)gy * W + gx);
    else
      v = make_float4(-INFINITY, -INFINITY, -INFINITY, -INFINITY);
    *reinterpret_cast<float4*>(&S[r * STR + 4 * G]) = v;
  }
  for (int i = tid; i < RROWS * MW; i += 256) {
    M0s[i] = 0;
    M1s[i] = 0;
  }
  __syncthreads();
  if (tid < NUNIT_M) {
    score_pass<0>(tid, x0, y0, S, nullptr, M0s, nullptr, nullptr, nullptr, nullptr,
                  nullptr, b);
  } else {  // 76 idle threads zero the hist during pass 0 (no barriers either side)
    for (int i = tid - NUNIT_M; i < HIST_BINS; i += 256 - NUNIT_M) Shist[i] = 0;
  }
  __syncthreads();
  if (tid < NUNIT_M)
    score_pass<1>(tid, x0, y0, S, M0s, M1s, nullptr, nullptr, nullptr, nullptr,
                  nullptr, b);
  __syncthreads();
  if (tid < NUNIT_E)
    score_pass<2>(tid, x0, y0, S, M1s, nullptr, list, &cnt_loc, cand, cand_count,
                  ghist, b);
  __syncthreads();
  // tail: copy list -> cand, accumulate 256-bin fine hist, sparse-merge to global
  uint32_t nblk = cnt_loc;
  uint32_t nmain = nblk < (uint32_t)LIST_CAP ? nblk : (uint32_t)LIST_CAP;
  if (tid == 0) base_g = atomicAdd(&cand_count[b], nmain);
  __syncthreads();
  uint32_t bg = base_g;
  for (uint32_t i = tid; i < nmain; i += 256) {
    uint64_t key = list[i];
    uint32_t pp = bg + i;
    if (pp < (uint32_t)CAND_CAP) cand[(size_t)b * CAND_CAP + pp] = key;
    int bin = (int)(uint32_t)(key >> 47) - HIST_BASE;  // = (score_bits>>15)-32256
    if (bin < 0) bin = 0;
    atomicAdd(&Shist[bin], 1u);
  }
  __syncthreads();
  {
    uint32_t v = Shist[tid];
    if (v) atomicAdd(&ghist[(size_t)b * HIST_BINS + tid], v);  // sparse bins only
  }
}

// ---------------- compact (threshold-find fused in, 256-bin hist) --------------------
// Each live block recomputes thr from ghist with a 64-wide suffix scan (redundant
// across blocks but fully parallel), filters its 1024-candidate slice, and zeroes
// rankg for every sel slot written. Dead blocks (beyond cand count) exit early.
__global__ void __launch_bounds__(1024) k_compact(const uint64_t* __restrict__ cand,
                                                  const uint32_t* __restrict__ cand_count,
                                                  const uint32_t* __restrict__ ghist,
                                                  uint64_t* __restrict__ sel,
                                                  uint32_t* __restrict__ sel_count,
                                                  uint32_t* __restrict__ rankg) {
  __shared__ uint64_t list[1024];
  __shared__ uint32_t cnt_loc, base_g;
  __shared__ uint32_t h[64];
  __shared__ uint64_t s_thr;
  const int b = blockIdx.y;
  uint32_t n = cand_count[b];
  if (n > (uint32_t)CAND_CAP) n = CAND_CAP;
  if (blockIdx.x * 1024u >= n) return;  // dead block: skip redundant scan
  const int tid = threadIdx.x;
  if (tid == 0) {
    cnt_loc = 0;
    s_thr = 0ull;
  }
  // bins 4*tid .. 4*tid+3 (256/4 = 64 loaders)
  const uint32_t* gh = ghist + (size_t)b * HIST_BINS;
  uint4 mybins = make_uint4(0u, 0u, 0u, 0u);
  if (tid < HIST_BINS / 4) {
    mybins = reinterpret_cast<const uint4*>(gh)[tid];
    h[tid] = mybins.x + mybins.y + mybins.z + mybins.w;
  }
  __syncthreads();
  for (int d = 1; d < 64; d <<= 1) {
    uint32_t v = 0;
    if (tid < 64) v = (tid + d < 64) ? h[tid + d] : 0u;
    __syncthreads();
    if (tid < 64) h[tid] += v;
    __syncthreads();
  }
  if (tid < 64) {
    uint32_t cum = h[tid];                       // count in bins >= 4*tid
    uint32_t nxt = (tid < 63) ? h[tid + 1] : 0u; // count in bins >= 4*(tid+1)
    if (cum >= (uint32_t)TOPK && nxt < (uint32_t)TOPK) {
      uint32_t run = nxt;
      uint32_t binv[4] = {mybins.x, mybins.y, mybins.z, mybins.w};
      int thrbin = 4 * tid;
#pragma unroll
      for (int j = 3; j >= 0; --j) {
        run += binv[j];
        if (run >= (uint32_t)TOPK) {
          thrbin = 4 * tid + j;
          break;
        }
      }
      if (thrbin > 0)
        s_thr = ((uint64_t)(uint32_t)(thrbin + HIST_BASE)) << 47;
      // thrbin == 0: underflow aggregate -> thr 0 (select all)
    }
  }
  __syncthreads();
  const uint64_t thr = s_thr;  // 0 => select all (fewer than TOPK, or bin-0 thr)
  uint32_t i = blockIdx.x * 1024 + tid;
  if (i < n) {
    uint64_t key = cand[(size_t)b * CAND_CAP + i];
    if (key >= thr) {
      uint32_t pos = atomicAdd(&cnt_loc, 1u);
      list[pos] = key;
    }
  }
  __syncthreads();
  uint32_t nblk = cnt_loc;
  if (tid == 0 && nblk > 0) base_g = atomicAdd(&sel_count[b], nblk);
  __syncthreads();
  if (nblk > 0 && (uint32_t)tid < nblk) {
    uint32_t pp = base_g + tid;
    if (pp < (uint32_t)SEL_CAP) {
      sel[(size_t)b * SEL_CAP + pp] = list[tid];
      rankg[(size_t)b * SEL_CAP + pp] = 0u;
    }
  }
}

// ---------------- tiled partial ranking ----------------------------------------------
__global__ void __launch_bounds__(RK_ME) k_rank_part(const uint64_t* __restrict__ sel,
                                                     const uint32_t* __restrict__ sel_count,
                                                     uint32_t* __restrict__ rankg) {
  __shared__ uint64_t keys[RK_CH];  // 8 KiB
  const int b = blockIdx.z;
  uint32_t n = sel_count[b];
  if (n > (uint32_t)SEL_CAP) n = SEL_CAP;
  const uint32_t me0 = blockIdx.x * RK_ME;
  const uint32_t c0 = blockIdx.y * RK_CH;
  if (me0 >= n || c0 >= n) return;
  const uint64_t* sb = sel + (size_t)b * SEL_CAP;
  uint32_t clen = n - c0;
  if (clen > (uint32_t)RK_CH) clen = RK_CH;
  for (uint32_t i = threadIdx.x; i < clen; i += RK_ME) keys[i] = sb[c0 + i];
  __syncthreads();
  const uint32_t me = me0 + threadIdx.x;
  if (me >= n) return;
  const uint64_t kme = sb[me];
  uint32_t rank = 0;
  uint32_t i = 0;
  for (; i + 8 <= clen; i += 8) {
    rank += (keys[i] > kme);
    rank += (keys[i + 1] > kme);
    rank += (keys[i + 2] > kme);
    rank += (keys[i + 3] > kme);
    rank += (keys[i + 4] > kme);
    rank += (keys[i + 5] > kme);
    rank += (keys[i + 6] > kme);
    rank += (keys[i + 7] > kme);
  }
  for (; i < clen; ++i) rank += (keys[i] > kme);
  if (rank) atomicAdd(&rankg[(size_t)b * SEL_CAP + me], rank);
}

// ---------------- refinement (scatter fused in): 8 lanes per sel item ----------------
__global__ void __launch_bounds__(256) k_refine(const float* __restrict__ scores,
                                                const uint64_t* __restrict__ sel,
                                                const uint32_t* __restrict__ sel_count,
                                                const uint32_t* __restrict__ rankg,
                                                float* __restrict__ out) {
  int gid = blockIdx.x * 256 + threadIdx.x;
  int idx = gid >> 3, ln = gid & 7;
  const int b = idx / SEL_CAP;
  const int i = idx % SEL_CAP;
  uint32_t n = sel_count[b];
  if (n > (uint32_t)SEL_CAP) n = SEL_CAP;
  if ((uint32_t)i >= n) return;  // uniform across the 8-lane group
  uint32_t r = rankg[(size_t)b * SEL_CAP + i];
  if (r >= (uint32_t)TOPK) return;  // uniform across the group
  uint64_t key = sel[(size_t)b * SEL_CAP + i];
  uint32_t flat = 0xFFFFFFFFu - (uint32_t)(key & 0xFFFFFFFFull);
  if (flat >= (uint32_t)(H * W)) flat = 0;  // safety guard
  const int ix = (int)(flat % W);
  const int iy = (int)(flat / W);
  const float* img = scores + (size_t)b * H * W;

  const int nt = (ln == 0) ? 4 : 3;
  float v[4];
  float mymax = -INFINITY;
#pragma unroll
  for (int q = 0; q < 4; ++q) {
    if (q < nt) {
      int t = ln + 8 * q;
      int y = iy + t / 5 - 2, x = ix + t % 5 - 2;
      float val = ((unsigned)x < (unsigned)W && (unsigned)y < (unsigned)H)
                      ? img[(size_t)y * W + x] : 0.0f;
      v[q] = val;
      mymax = fmaxf(mymax, val);
    }
  }
#pragma unroll
  for (int m = 1; m < 8; m <<= 1) mymax = fmaxf(mymax, __shfl_xor(mymax, m));
  float e[4];
  float sum = 0.f, sx = 0.f, sy = 0.f;
#pragma unroll
  for (int q = 0; q < 4; ++q) {
    if (q < nt) {
      int t = ln + 8 * q;
      float ev = expf((v[q] - mymax) / 0.1f);
      e[q] = ev;
      sum += ev;
      sx += ev * (float)(t % 5 - 2);
      sy += ev * (float)(t / 5 - 2);
    }
  }
#pragma unroll
  for (int m = 1; m < 8; m <<= 1) {
    sum += __shfl_xor(sum, m);
    sx += __shfl_xor(sx, m);
    sy += __shfl_xor(sy, m);
  }
  float rx = sx / sum, ry = sy / sum;
  float dsp = 0.f;
#pragma unroll
  for (int q = 0; q < 4; ++q) {
    if (q < nt) {
      int t = ln + 8 * q;
      float dx = ((float)(t % 5 - 2) - rx) * 0.5f;
      float dy = ((float)(t / 5 - 2) - ry) * 0.5f;
      dsp += e[q] * (dx * dx + dy * dy);
    }
  }
#pragma unroll
  for (int m = 1; m < 8; m <<= 1) dsp += __shfl_xor(dsp, m);
  if (ln != 0) return;
  dsp /= sum;
  float kx = ((float)ix + rx) / 1023.0f * 2.0f - 1.0f;
  float ky = ((float)iy + ry) / 1023.0f * 2.0f - 1.0f;
  float px = (kx + 1.0f) * 0.5f * 1023.0f;
  float py = (ky + 1.0f) * 0.5f * 1023.0f;
  float x0f = floorf(px), y0f = floorf(py);
  float wx1 = px - x0f, wx0 = 1.0f - wx1;
  float wy1 = py - y0f, wy0 = 1.0f - wy1;
  int x0 = (int)x0f, y0 = (int)y0f;
  float sc = 0.0f;
  {
    int xs[2] = {x0, x0 + 1};
    int ys[2] = {y0, y0 + 1};
    float wxs[2] = {wx0, wx1};
    float wys[2] = {wy0, wy1};
#pragma unroll
    for (int yy = 0; yy < 2; ++yy)
#pragma unroll
      for (int xx = 0; xx < 2; ++xx) {
        int xi = xs[xx], yi = ys[yy];
        bool valid = (xi >= 0 && xi < W && yi >= 0 && yi < H);
        int xc = min(max(xi, 0), W - 1);
        int yc = min(max(yi, 0), H - 1);
        float vv = valid ? img[(size_t)yc * W + xc] : 0.0f;
        sc += vv * (wxs[xx] * wys[yy]);
      }
  }
  out[((size_t)b * TOPK + r) * 2 + 0] = kx;
  out[((size_t)b * TOPK + r) * 2 + 1] = ky;
  out[(size_t)B * TOPK * 2 + (size_t)b * TOPK + r] = sc;
  out[(size_t)B * TOPK * 3 + (size_t)b * TOPK + r] = dsp;
}

}  // namespace

extern "C" void kernel_launch(void* const* d_in, const int* in_sizes, int n_in,
                              void* d_out, int out_size, void* d_ws, size_t ws_size,
                              hipStream_t stream) {
  const float* scores = (const float*)d_in[0];
  float* out = (float*)d_out;
  char* ws = (char*)d_ws;

  uint32_t* cnt = (uint32_t*)(ws + OFF_CNT);
  uint32_t* cand_count = cnt;                    // [B]
  uint32_t* sel_count  = cnt + 8;                // [B]
  uint32_t* ghist = (uint32_t*)(ws + OFF_GH);    // [B][HIST_BINS]
  uint32_t* rankg = (uint32_t*)(ws + OFF_RANK);  // [B][SEL_CAP]
  uint64_t* sel  = (uint64_t*)(ws + OFF_SEL);
  uint64_t* cand = (uint64_t*)(ws + OFF_CAND);

  hipMemsetAsync(ws + OFF_CNT, 0, MEMSET_BYTES, stream);

  k_nms<<<dim3(W / 64, H / 64, B), 256, 0, stream>>>(scores, cand, cand_count, ghist);
  k_compact<<<dim3(CAND_CAP / 1024, B), 1024, 0, stream>>>(cand, cand_count, ghist,
                                                           sel, sel_count, rankg);
  k_rank_part<<<dim3(SEL_CAP / RK_ME, SEL_CAP / RK_CH, B), RK_ME, 0, stream>>>(
      sel, sel_count, rankg);
  k_refine<<<(B * SEL_CAP * 8) / 256, 256, 0, stream>>>(scores, sel, sel_count, rankg,
                                                        out);
}